// Round 7
// baseline (324.087 us; speedup 1.0000x reference)
//
#include <hip/hip_runtime.h>

#define F 16
#define BSHIFT 8
#define NPB 256           // nodes per bucket = 1<<BSHIFT
#define NB 391            // buckets for N=100000: ceil(100000/256)
#define CH 4096           // edges per reorder block

// ========================= fast path kernels ================================

// block-privatized histogram of dst>>8 into bcount[NB], int4-vectorized
__global__ void hist_kernel(const int* __restrict__ dst, unsigned* __restrict__ bcount, int E) {
    __shared__ unsigned lc[NB];
    for (int i = threadIdx.x; i < NB; i += blockDim.x) lc[i] = 0;
    __syncthreads();
    int E4 = E >> 2;
    const int4* d4 = (const int4*)dst;
    int stride = gridDim.x * blockDim.x;
    for (int e = blockIdx.x * blockDim.x + threadIdx.x; e < E4; e += stride) {
        int4 v = d4[e];
        atomicAdd(&lc[((unsigned)v.x) >> BSHIFT], 1u);
        atomicAdd(&lc[((unsigned)v.y) >> BSHIFT], 1u);
        atomicAdd(&lc[((unsigned)v.z) >> BSHIFT], 1u);
        atomicAdd(&lc[((unsigned)v.w) >> BSHIFT], 1u);
    }
    for (int e = E4 * 4 + blockIdx.x * blockDim.x + threadIdx.x; e < E; e += stride)
        atomicAdd(&lc[((unsigned)dst[e]) >> BSHIFT], 1u);
    __syncthreads();
    for (int i = threadIdx.x; i < NB; i += blockDim.x) {
        unsigned c = lc[i];
        if (c) atomicAdd(&bcount[i], c);
    }
}

// single-block exclusive scan of NB counts -> off[], cursor[] (cursor padded x16)
__global__ void scan_kernel(const unsigned* __restrict__ bcount, int* __restrict__ off,
                            unsigned* __restrict__ cursor, int E) {
    __shared__ unsigned s[2048];
    int t = threadIdx.x; // 1024 threads
    unsigned c0 = (t < NB) ? bcount[t] : 0u;
    unsigned c1 = (t + 1024 < NB) ? bcount[t + 1024] : 0u;
    s[t] = c0; s[t + 1024] = c1;
    __syncthreads();
    for (int d = 1; d < 2048; d <<= 1) {
        unsigned a  = (t >= d) ? s[t - d] : 0u;
        unsigned bv = (t + 1024 >= d) ? s[t + 1024 - d] : 0u;
        __syncthreads();
        s[t] += a; s[t + 1024] += bv;
        __syncthreads();
    }
    if (t < NB)       { unsigned ex = s[t] - c0;       off[t] = ex;       cursor[t * 16] = ex; }
    if (t + 1024 < NB){ unsigned ex = s[t+1024] - c1;  off[t+1024] = ex;  cursor[(t+1024)*16] = ex; }
    if (t == 0) off[NB] = E;
}

// bucket reorder, LDS counting-sort per 4096-edge chunk. 512 threads/block.
// rec = src | (dst&255)<<17
__global__ void reorder_kernel(const int* __restrict__ src, const int* __restrict__ dst,
                               unsigned* __restrict__ cursor, unsigned* __restrict__ recs, int E) {
    __shared__ unsigned lsorted[CH];
    __shared__ unsigned short lbkt[CH];
    __shared__ unsigned lstart[NB + 1];
    __shared__ unsigned lcur[NB];
    __shared__ int ldelta[NB];
    int t = threadIdx.x, b = blockIdx.x;
    int e0 = b * CH;
    int cnt_e = E - e0; if (cnt_e > CH) cnt_e = CH;
    int i4 = cnt_e >> 2;
    const int4* dst4 = (const int4*)(dst + e0);
    const int4* src4 = (const int4*)(src + e0);

    for (int i = t; i < NB; i += 512) lcur[i] = 0;   // reuse lcur as counts
    __syncthreads();
    // phase 1: histogram (int4 coalesced)
    for (int i = t; i < i4; i += 512) {
        int4 d = dst4[i];
        atomicAdd(&lcur[((unsigned)d.x) >> BSHIFT], 1u);
        atomicAdd(&lcur[((unsigned)d.y) >> BSHIFT], 1u);
        atomicAdd(&lcur[((unsigned)d.z) >> BSHIFT], 1u);
        atomicAdd(&lcur[((unsigned)d.w) >> BSHIFT], 1u);
    }
    for (int i = i4 * 4 + t; i < cnt_e; i += 512)
        atomicAdd(&lcur[((unsigned)dst[e0 + i]) >> BSHIFT], 1u);
    __syncthreads();
    // phase 2: exclusive scan of NB counts by wave 0
    if (t < 64) {
        unsigned run = 0;
        for (int c = 0; c < NB; c += 64) {
            int idx = c + t;
            unsigned v = (idx < NB) ? lcur[idx] : 0u;
            unsigned inc = v;
#pragma unroll
            for (int d = 1; d < 64; d <<= 1) {
                unsigned o = __shfl_up(inc, d, 64);
                if (t >= d) inc += o;
            }
            if (idx <= NB) lstart[idx] = run + inc - v;
            unsigned tot = __shfl(inc, 63, 64);
            if (t == 63 && idx < NB) lstart[idx + 1] = run + inc;
            run += tot;
        }
        if (t == 0) lstart[NB] = (unsigned)cnt_e;
    }
    __syncthreads();
    // phase 3: reserve global ranges, init cursors
    for (int i = t; i < NB; i += 512) {
        unsigned st = lstart[i];
        unsigned cnt = lstart[i + 1] - st;
        lcur[i] = st;
        if (cnt) {
            unsigned g = atomicAdd(&cursor[i * 16], cnt);
            ldelta[i] = (int)g - (int)st;
        }
    }
    __syncthreads();
    // phase 4: LDS scatter into sorted order (int4 reads)
    for (int i = t; i < i4; i += 512) {
        int4 d = dst4[i];
        int4 s = src4[i];
        unsigned dd, bk, pos;
        dd = (unsigned)d.x; bk = dd >> BSHIFT; pos = atomicAdd(&lcur[bk], 1u);
        lsorted[pos] = (unsigned)s.x | ((dd & (NPB - 1u)) << 17); lbkt[pos] = (unsigned short)bk;
        dd = (unsigned)d.y; bk = dd >> BSHIFT; pos = atomicAdd(&lcur[bk], 1u);
        lsorted[pos] = (unsigned)s.y | ((dd & (NPB - 1u)) << 17); lbkt[pos] = (unsigned short)bk;
        dd = (unsigned)d.z; bk = dd >> BSHIFT; pos = atomicAdd(&lcur[bk], 1u);
        lsorted[pos] = (unsigned)s.z | ((dd & (NPB - 1u)) << 17); lbkt[pos] = (unsigned short)bk;
        dd = (unsigned)d.w; bk = dd >> BSHIFT; pos = atomicAdd(&lcur[bk], 1u);
        lsorted[pos] = (unsigned)s.w | ((dd & (NPB - 1u)) << 17); lbkt[pos] = (unsigned short)bk;
    }
    for (int i = i4 * 4 + t; i < cnt_e; i += 512) {
        unsigned dd = (unsigned)dst[e0 + i];
        unsigned bk = dd >> BSHIFT;
        unsigned pos = atomicAdd(&lcur[bk], 1u);
        lsorted[pos] = (unsigned)src[e0 + i] | ((dd & (NPB - 1u)) << 17);
        lbkt[pos] = (unsigned short)bk;
    }
    __syncthreads();
    // phase 5: run-contiguous write-out
    for (int i = t; i < cnt_e; i += 512) {
        unsigned bk = lbkt[i];
        recs[ldelta[bk] + i] = lsorted[i];
    }
}

// per-bucket node-granularity sort: recs (bucket-sorted) -> srcs (dst-sorted),
// plus CSR offsets noff[] and dinv[] from the LDS degree histogram. 1024 thr.
__global__ void sort2_kernel(const unsigned* __restrict__ recs, const int* __restrict__ off,
                             unsigned* __restrict__ srcs, int* __restrict__ noff,
                             float* __restrict__ dinv, int n, int E) {
    __shared__ unsigned cnt[NPB];
    __shared__ unsigned curs[NPB];
    __shared__ unsigned wtot[4];
    int t = threadIdx.x, b = blockIdx.x;   // 1024 threads
    if (t < NPB) cnt[t] = 0;
    __syncthreads();
    int e0 = off[b], e1 = off[b + 1];
    for (int e = e0 + t; e < e1; e += 1024) atomicAdd(&cnt[recs[e] >> 17], 1u);
    __syncthreads();
    if (t < NPB) {
        unsigned c = cnt[t];
        unsigned inc = c;
        int lane = t & 63, w = t >> 6;
#pragma unroll
        for (int d = 1; d < 64; d <<= 1) {
            unsigned o = __shfl_up(inc, d, 64);
            if (lane >= d) inc += o;
        }
        if (lane == 63) wtot[w] = inc;
        __syncthreads();
        unsigned wbase = 0;
        for (int i = 0; i < w; ++i) wbase += wtot[i];
        unsigned ex = wbase + inc - c;
        curs[t] = (unsigned)e0 + ex;
        int node = b * NPB + t;
        if (node < n) {
            noff[node] = e0 + (int)ex;
            dinv[node] = rsqrtf((float)c + 1.0f);
        }
    } else {
        __syncthreads();
    }
    if (b == (int)gridDim.x - 1 && t == 0) noff[n] = E;
    __syncthreads();
    for (int e = e0 + t; e < e1; e += 1024) {
        unsigned rec = recs[e];
        unsigned pos = atomicAdd(&curs[rec >> 17], 1u);
        srcs[pos] = rec & 0x1FFFFu;
    }
}

// h[i,:] = (x[i,:] @ W) * dinv[i] — writes SPLIT halves h0[N][8], h1[N][8].
// 64 nodes/block, 4 lanes/node.
__global__ void linear_split_kernel(const float* __restrict__ in, const float* __restrict__ dinv,
                                    const float* __restrict__ W,
                                    float4* __restrict__ o0, float4* __restrict__ o1, int n) {
    __shared__ float Ws[F * F];
    __shared__ float As[64][F + 1];
    int t = threadIdx.x;
    Ws[t] = W[t];
    int g = t >> 2, c = t & 3;
    int node = blockIdx.x * 64 + g;
    float4 v = {0.f, 0.f, 0.f, 0.f};
    if (node < n) v = ((const float4*)in)[(size_t)node * 4 + c];
    As[g][c * 4 + 0] = v.x; As[g][c * 4 + 1] = v.y;
    As[g][c * 4 + 2] = v.z; As[g][c * 4 + 3] = v.w;
    __syncthreads();
    if (node < n) {
        float di = dinv[node];
        float4 o = {0.f, 0.f, 0.f, 0.f};
        int j = c * 4;
#pragma unroll
        for (int k = 0; k < F; ++k) {
            float ak = As[g][k];
            o.x += ak * Ws[k * F + j + 0];
            o.y += ak * Ws[k * F + j + 1];
            o.z += ak * Ws[k * F + j + 2];
            o.w += ak * Ws[k * F + j + 3];
        }
        o.x *= di; o.y *= di; o.z *= di; o.w *= di;
        if (c < 2) o0[(size_t)node * 2 + c] = o;
        else       o1[(size_t)node * 2 + (c - 2)] = o;
    }
}

// half-feature CSR aggregation pass. hin = one 3.2MB half array [N][8] (L2-resident).
// 128 nodes/block, 2 lanes/node (c in {0,1} -> float4 within the half-row).
// v = dinv*(sum_edges hin[src] + hin[node]) + bias8[c]
// mode 0: alo[node] = relu(v)                              (mid layer, low half)
// mode 1: a = [alo_in[node], relu(v)]; full 16x16 matmul:  g0/g1 = (a@Wn)*dinv
// mode 2: out[node][0..7]  = v                             (final, low half)
// mode 3: out[node][8..15] = v                             (final, high half)
__global__ void agg_half_kernel(const float4* __restrict__ hin, const unsigned* __restrict__ srcs,
                                const int* __restrict__ noff, const float* __restrict__ dinv,
                                const float* __restrict__ Wn, const float* __restrict__ bias8,
                                const float4* __restrict__ alo_in,
                                float4* __restrict__ o0, float4* __restrict__ o1,
                                int n, int mode) {
    __shared__ float al[128][F + 1];
    __shared__ float Ws[F * F];
    int t = threadIdx.x;
    int g = t >> 1, c = t & 1;
    if (mode == 1) Ws[t] = Wn[t];
    int node = blockIdx.x * 128 + g;
    float di = 0.f;
    float4 val = {0.f, 0.f, 0.f, 0.f};
    if (node < n) {
        di = dinv[node];
        int e0 = noff[node], e1 = noff[node + 1];
        float4 s0 = {0,0,0,0}, s1 = {0,0,0,0}, s2 = {0,0,0,0}, s3 = {0,0,0,0};
        int e = e0;
        for (; e + 4 <= e1; e += 4) {
            unsigned ia = __builtin_nontemporal_load(srcs + e);
            unsigned ib = __builtin_nontemporal_load(srcs + e + 1);
            unsigned ic = __builtin_nontemporal_load(srcs + e + 2);
            unsigned id = __builtin_nontemporal_load(srcs + e + 3);
            float4 va = hin[(size_t)ia * 2 + c];
            float4 vb = hin[(size_t)ib * 2 + c];
            float4 vc = hin[(size_t)ic * 2 + c];
            float4 vd = hin[(size_t)id * 2 + c];
            s0.x += va.x; s0.y += va.y; s0.z += va.z; s0.w += va.w;
            s1.x += vb.x; s1.y += vb.y; s1.z += vb.z; s1.w += vb.w;
            s2.x += vc.x; s2.y += vc.y; s2.z += vc.z; s2.w += vc.w;
            s3.x += vd.x; s3.y += vd.y; s3.z += vd.z; s3.w += vd.w;
        }
        for (; e < e1; ++e) {
            unsigned ia = __builtin_nontemporal_load(srcs + e);
            float4 va = hin[(size_t)ia * 2 + c];
            s0.x += va.x; s0.y += va.y; s0.z += va.z; s0.w += va.w;
        }
        float4 self = hin[(size_t)node * 2 + c];
        float4 bi = ((const float4*)bias8)[c];
        val.x = di * ((s0.x + s1.x) + (s2.x + s3.x) + self.x) + bi.x;
        val.y = di * ((s0.y + s1.y) + (s2.y + s3.y) + self.y) + bi.y;
        val.z = di * ((s0.z + s1.z) + (s2.z + s3.z) + self.z) + bi.z;
        val.w = di * ((s0.w + s1.w) + (s2.w + s3.w) + self.w) + bi.w;
        if (mode <= 1) {   // relu for mid layer
            val.x = fmaxf(val.x, 0.f); val.y = fmaxf(val.y, 0.f);
            val.z = fmaxf(val.z, 0.f); val.w = fmaxf(val.w, 0.f);
        }
    }
    if (mode == 0) {
        if (node < n) o0[(size_t)node * 2 + c] = val;
    } else if (mode == 1) {
        if (node < n) {
            float4 av = alo_in[(size_t)node * 2 + c];
            al[g][c * 4 + 0] = av.x; al[g][c * 4 + 1] = av.y;
            al[g][c * 4 + 2] = av.z; al[g][c * 4 + 3] = av.w;
            al[g][8 + c * 4 + 0] = val.x; al[g][8 + c * 4 + 1] = val.y;
            al[g][8 + c * 4 + 2] = val.z; al[g][8 + c * 4 + 3] = val.w;
        }
        __syncthreads();
        if (node < n) {
            int j0 = c * 8;
            float4 oa = {0,0,0,0}, ob = {0,0,0,0};
#pragma unroll
            for (int k = 0; k < F; ++k) {
                float ak = al[g][k];
                oa.x += ak * Ws[k * F + j0 + 0];
                oa.y += ak * Ws[k * F + j0 + 1];
                oa.z += ak * Ws[k * F + j0 + 2];
                oa.w += ak * Ws[k * F + j0 + 3];
                ob.x += ak * Ws[k * F + j0 + 4];
                ob.y += ak * Ws[k * F + j0 + 5];
                ob.z += ak * Ws[k * F + j0 + 6];
                ob.w += ak * Ws[k * F + j0 + 7];
            }
            oa.x *= di; oa.y *= di; oa.z *= di; oa.w *= di;
            ob.x *= di; ob.y *= di; ob.z *= di; ob.w *= di;
            float4* dstp = (c == 0) ? o0 : o1;
            dstp[(size_t)node * 2 + 0] = oa;
            dstp[(size_t)node * 2 + 1] = ob;
        }
    } else if (mode == 2) {
        if (node < n) o0[(size_t)node * 4 + c] = val;
    } else {
        if (node < n) o0[(size_t)node * 4 + 2 + c] = val;
    }
}

// ========================= fallback (R1) kernels ============================

__global__ void deg_kernel(const int* __restrict__ dst, float* __restrict__ deg, int E) {
    int e = blockIdx.x * blockDim.x + threadIdx.x;
    if (e < E) atomicAdd(&deg[dst[e]], 1.0f);
}
__global__ void dinv_kernel(float* __restrict__ deg, int n) {
    int i = blockIdx.x * blockDim.x + threadIdx.x;
    if (i < n) deg[i] = rsqrtf(deg[i] + 1.0f);
}
__global__ void linear2_kernel(const float* __restrict__ in, const float* __restrict__ acc,
                               const float* __restrict__ dinv, const float* __restrict__ W,
                               const float* __restrict__ bias, float* __restrict__ out,
                               int n, int mode) {
    __shared__ float Ws[F * F];
    __shared__ float As[16][F + 1];
    int t = threadIdx.x;
    Ws[t] = W[t];
    int nb = t >> 4, j = t & 15;
    int i = blockIdx.x * 16 + nb;
    float di = 0.f, v = 0.f;
    if (i < n) {
        di = dinv[i]; v = in[i * F + j];
        if (mode) { v = di * (acc[i * F + j] + v) + bias[j]; v = fmaxf(v, 0.f); }
    }
    As[nb][j] = v;
    __syncthreads();
    if (i < n) {
        float s = 0.f;
#pragma unroll
        for (int k = 0; k < F; ++k) s += As[nb][k] * Ws[k * F + j];
        out[i * F + j] = s * di;
    }
}
__global__ void scatter_kernel(const int* __restrict__ src, const int* __restrict__ dst,
                               const float* __restrict__ h, float* __restrict__ acc, int E) {
    int t = blockIdx.x * blockDim.x + threadIdx.x;
    int e = t >> 4, j = t & 15;
    if (e < E) atomicAdd(&acc[dst[e] * F + j], h[src[e] * F + j]);
}
__global__ void out_kernel(const float* __restrict__ acc, const float* __restrict__ h,
                           const float* __restrict__ dinv, const float* __restrict__ bias,
                           float* __restrict__ out, int n) {
    int t = blockIdx.x * blockDim.x + threadIdx.x;
    if (t < n * F) {
        int i = t >> 4, j = t & 15;
        out[t] = dinv[i] * (acc[t] + h[t]) + bias[j];
    }
}

// ========================= launch ===========================================

extern "C" void kernel_launch(void* const* d_in, const int* in_sizes, int n_in,
                              void* d_out, int out_size, void* d_ws, size_t ws_size,
                              hipStream_t stream) {
    const float* x  = (const float*)d_in[0];
    const int*   ei = (const int*)d_in[1];
    const float* W1 = (const float*)d_in[2];
    const float* b1 = (const float*)d_in[3];
    const float* W2 = (const float*)d_in[4];
    const float* b2 = (const float*)d_in[5];
    float* outp = (float*)d_out;

    const int N = in_sizes[0] / F;
    const int E = in_sizes[1] / 2;
    const int* src = ei;
    const int* dst = ei + E;

    const int nb_rt = (N + NPB - 1) >> BSHIFT;
    // ws layout (4B units): dinv[N] | h0[8N] (g0 aliases) | h1[8N] | alo[8N] | g1[8N] |
    //                       recs[E] | srcs[E] | noff[N+1] | bcount[NB] | off[NB+1] | cursor[16*NB]
    size_t need = sizeof(float) * ((size_t)N * 33 + (N + 1)
                                   + 2 * (size_t)E + NB + (NB + 1) + 16 * NB);

    if (nb_rt == NB && ws_size >= need) {
        float* dinv = (float*)d_ws;
        float* h0 = dinv + N;                 // layer-1 low half; later g0 (layer-2 low)
        float* h1 = h0 + (size_t)8 * N;       // layer-1 high half
        float* alo = h1 + (size_t)8 * N;      // relu'd low half of a1
        float* g1 = alo + (size_t)8 * N;      // layer-2 high half
        unsigned* recs = (unsigned*)(g1 + (size_t)8 * N);
        unsigned* srcs = recs + E;
        int* noff = (int*)(srcs + E);
        unsigned* bcount = (unsigned*)(noff + N + 1);
        int* off = (int*)(bcount + NB);
        unsigned* cursor = (unsigned*)(off + NB + 1);
        float* g0 = h0;                       // alias: h0 dead once mode-0 pass consumed it... (see order)

        hipMemsetAsync(bcount, 0, NB * sizeof(unsigned), stream);
        hist_kernel<<<512, 256, 0, stream>>>(dst, bcount, E);
        scan_kernel<<<1, 1024, 0, stream>>>(bcount, off, cursor, E);
        reorder_kernel<<<(E + CH - 1) / CH, 512, 0, stream>>>(src, dst, cursor, recs, E);
        sort2_kernel<<<NB, 1024, 0, stream>>>(recs, off, srcs, noff, dinv, N, E);
        linear_split_kernel<<<(N + 63) / 64, 256, 0, stream>>>(x, dinv, W1, (float4*)h0, (float4*)h1, N);
        int agrid = (N + 127) / 128;
        // mid layer: pass 0 gathers h0 -> alo; pass 1 gathers h1, joins alo, @W2 -> g0,g1
        agg_half_kernel<<<agrid, 256, 0, stream>>>((const float4*)h0, srcs, noff, dinv,
                                                   nullptr, b1, nullptr,
                                                   (float4*)alo, nullptr, N, 0);
        agg_half_kernel<<<agrid, 256, 0, stream>>>((const float4*)h1, srcs, noff, dinv,
                                                   W2, b1 + 8, (const float4*)alo,
                                                   (float4*)g0, (float4*)g1, N, 1);
        // final layer: pass 0 gathers g0 -> out[:,0:8]; pass 1 gathers g1 -> out[:,8:16]
        agg_half_kernel<<<agrid, 256, 0, stream>>>((const float4*)g0, srcs, noff, dinv,
                                                   nullptr, b2, nullptr,
                                                   (float4*)outp, nullptr, N, 2);
        agg_half_kernel<<<agrid, 256, 0, stream>>>((const float4*)g1, srcs, noff, dinv,
                                                   nullptr, b2 + 8, nullptr,
                                                   (float4*)outp, nullptr, N, 3);
    } else {
        // R1 fallback: atomic scatter path (13.2MB ws)
        float* dinv = (float*)d_ws;
        float* h = dinv + N;
        float* acc = h + (size_t)F * N;
        hipMemsetAsync(dinv, 0, (size_t)N * sizeof(float), stream);
        hipMemsetAsync(acc, 0, (size_t)F * N * sizeof(float), stream);
        deg_kernel<<<(E + 255) / 256, 256, 0, stream>>>(dst, dinv, E);
        dinv_kernel<<<(N + 255) / 256, 256, 0, stream>>>(dinv, N);
        linear2_kernel<<<(N + 15) / 16, 256, 0, stream>>>(x, nullptr, dinv, W1, nullptr, h, N, 0);
        scatter_kernel<<<((size_t)E * F + 255) / 256, 256, 0, stream>>>(src, dst, h, acc, E);
        linear2_kernel<<<(N + 15) / 16, 256, 0, stream>>>(h, acc, dinv, W2, b1, h, N, 1);
        hipMemsetAsync(acc, 0, (size_t)F * N * sizeof(float), stream);
        scatter_kernel<<<((size_t)E * F + 255) / 256, 256, 0, stream>>>(src, dst, h, acc, E);
        out_kernel<<<((size_t)N * F + 255) / 256, 256, 0, stream>>>(acc, h, dinv, b2, outp, N);
    }
}

// Round 8
// 240.940 us; speedup vs baseline: 1.3451x; 1.3451x over previous
//
#include <hip/hip_runtime.h>

#define F 16
#define BSHIFT 8
#define NPB 256           // nodes per bucket = 1<<BSHIFT
#define NB 391            // buckets for N=100000: ceil(100000/256)
#define CH 8192           // edges per reorder block

// ========================= fast path kernels ================================

// block-privatized histogram of dst>>8 into bcount[NB], int4-vectorized
__global__ void hist_kernel(const int* __restrict__ dst, unsigned* __restrict__ bcount, int E) {
    __shared__ unsigned lc[NB];
    for (int i = threadIdx.x; i < NB; i += blockDim.x) lc[i] = 0;
    __syncthreads();
    int E4 = E >> 2;
    const int4* d4 = (const int4*)dst;
    int stride = gridDim.x * blockDim.x;
    for (int e = blockIdx.x * blockDim.x + threadIdx.x; e < E4; e += stride) {
        int4 v = d4[e];
        atomicAdd(&lc[((unsigned)v.x) >> BSHIFT], 1u);
        atomicAdd(&lc[((unsigned)v.y) >> BSHIFT], 1u);
        atomicAdd(&lc[((unsigned)v.z) >> BSHIFT], 1u);
        atomicAdd(&lc[((unsigned)v.w) >> BSHIFT], 1u);
    }
    for (int e = E4 * 4 + blockIdx.x * blockDim.x + threadIdx.x; e < E; e += stride)
        atomicAdd(&lc[((unsigned)dst[e]) >> BSHIFT], 1u);
    __syncthreads();
    for (int i = threadIdx.x; i < NB; i += blockDim.x) {
        unsigned c = lc[i];
        if (c) atomicAdd(&bcount[i], c);
    }
}

// single-block exclusive scan of NB counts -> off[], cursor[] (cursor padded x16)
__global__ void scan_kernel(const unsigned* __restrict__ bcount, int* __restrict__ off,
                            unsigned* __restrict__ cursor, int E) {
    __shared__ unsigned s[2048];
    int t = threadIdx.x; // 1024 threads
    unsigned c0 = (t < NB) ? bcount[t] : 0u;
    unsigned c1 = (t + 1024 < NB) ? bcount[t + 1024] : 0u;
    s[t] = c0; s[t + 1024] = c1;
    __syncthreads();
    for (int d = 1; d < 2048; d <<= 1) {
        unsigned a  = (t >= d) ? s[t - d] : 0u;
        unsigned bv = (t + 1024 >= d) ? s[t + 1024 - d] : 0u;
        __syncthreads();
        s[t] += a; s[t + 1024] += bv;
        __syncthreads();
    }
    if (t < NB)       { unsigned ex = s[t] - c0;       off[t] = ex;       cursor[t * 16] = ex; }
    if (t + 1024 < NB){ unsigned ex = s[t+1024] - c1;  off[t+1024] = ex;  cursor[(t+1024)*16] = ex; }
    if (t == 0) off[NB] = E;
}

// bucket reorder, LDS counting-sort per 8192-edge chunk. 512 threads/block.
// LDS ~36.7KB -> 4 blocks/CU (full occupancy). rec = src | (dst&255)<<17
__global__ __launch_bounds__(512) void
reorder_kernel(const int* __restrict__ src, const int* __restrict__ dst,
               unsigned* __restrict__ cursor, unsigned* __restrict__ recs, int E) {
    __shared__ unsigned lsorted[CH];
    __shared__ unsigned lstart[NB + 1];
    __shared__ unsigned lcur[NB];
    __shared__ int ldelta[NB];
    int t = threadIdx.x, b = blockIdx.x;
    int e0 = b * CH;
    int cnt_e = E - e0; if (cnt_e > CH) cnt_e = CH;
    int i4 = cnt_e >> 2;
    const int4* dst4 = (const int4*)(dst + e0);
    const int4* src4 = (const int4*)(src + e0);

    for (int i = t; i < NB; i += 512) lcur[i] = 0;   // lcur = counts for now
    __syncthreads();
    // phase 1: histogram (int4 coalesced)
    for (int i = t; i < i4; i += 512) {
        int4 d = dst4[i];
        atomicAdd(&lcur[((unsigned)d.x) >> BSHIFT], 1u);
        atomicAdd(&lcur[((unsigned)d.y) >> BSHIFT], 1u);
        atomicAdd(&lcur[((unsigned)d.z) >> BSHIFT], 1u);
        atomicAdd(&lcur[((unsigned)d.w) >> BSHIFT], 1u);
    }
    for (int i = i4 * 4 + t; i < cnt_e; i += 512)
        atomicAdd(&lcur[((unsigned)dst[e0 + i]) >> BSHIFT], 1u);
    __syncthreads();
    // phase 2: exclusive scan of NB counts by wave 0
    if (t < 64) {
        unsigned run = 0;
        for (int c = 0; c < NB; c += 64) {
            int idx = c + t;
            unsigned v = (idx < NB) ? lcur[idx] : 0u;
            unsigned inc = v;
#pragma unroll
            for (int d = 1; d < 64; d <<= 1) {
                unsigned o = __shfl_up(inc, d, 64);
                if (t >= d) inc += o;
            }
            if (idx < NB) lstart[idx] = run + inc - v;
            run += __shfl(inc, 63, 64);
        }
        if (t == 0) lstart[NB] = (unsigned)cnt_e;
    }
    __syncthreads();
    // phase 3: reserve global ranges, init scatter cursors
    for (int i = t; i < NB; i += 512) {
        unsigned st = lstart[i];
        unsigned cnt = lstart[i + 1] - st;
        lcur[i] = st;
        if (cnt) {
            unsigned g = atomicAdd(&cursor[i * 16], cnt);
            ldelta[i] = (int)g - (int)st;
        }
    }
    __syncthreads();
    // phase 4: LDS scatter into sorted order (int4 reads)
    for (int i = t; i < i4; i += 512) {
        int4 d = dst4[i];
        int4 s = src4[i];
        unsigned dd, bk, pos;
        dd = (unsigned)d.x; bk = dd >> BSHIFT; pos = atomicAdd(&lcur[bk], 1u);
        lsorted[pos] = (unsigned)s.x | ((dd & (NPB - 1u)) << 17);
        dd = (unsigned)d.y; bk = dd >> BSHIFT; pos = atomicAdd(&lcur[bk], 1u);
        lsorted[pos] = (unsigned)s.y | ((dd & (NPB - 1u)) << 17);
        dd = (unsigned)d.z; bk = dd >> BSHIFT; pos = atomicAdd(&lcur[bk], 1u);
        lsorted[pos] = (unsigned)s.z | ((dd & (NPB - 1u)) << 17);
        dd = (unsigned)d.w; bk = dd >> BSHIFT; pos = atomicAdd(&lcur[bk], 1u);
        lsorted[pos] = (unsigned)s.w | ((dd & (NPB - 1u)) << 17);
    }
    for (int i = i4 * 4 + t; i < cnt_e; i += 512) {
        unsigned dd = (unsigned)dst[e0 + i];
        unsigned bk = dd >> BSHIFT;
        unsigned pos = atomicAdd(&lcur[bk], 1u);
        lsorted[pos] = (unsigned)src[e0 + i] | ((dd & (NPB - 1u)) << 17);
    }
    __syncthreads();
    // phase 5: run-contiguous write-out; bucket of slot i via binary search in lstart
    for (int i = t; i < cnt_e; i += 512) {
        int lo = 0, hi = NB;   // lstart[lo] <= i < lstart[hi]
        while (hi - lo > 1) {
            int m = (lo + hi) >> 1;
            if (lstart[m] <= (unsigned)i) lo = m; else hi = m;
        }
        recs[ldelta[lo] + i] = lsorted[i];
    }
}

// per-bucket node-granularity sort: recs (bucket-sorted) -> srcs (dst-sorted),
// plus CSR offsets noff[] and dinv[] from the LDS degree histogram. 1024 thr.
__global__ void sort2_kernel(const unsigned* __restrict__ recs, const int* __restrict__ off,
                             unsigned* __restrict__ srcs, int* __restrict__ noff,
                             float* __restrict__ dinv, int n, int E) {
    __shared__ unsigned cnt[NPB];
    __shared__ unsigned curs[NPB];
    __shared__ unsigned wtot[4];
    int t = threadIdx.x, b = blockIdx.x;   // 1024 threads
    if (t < NPB) cnt[t] = 0;
    __syncthreads();
    int e0 = off[b], e1 = off[b + 1];
    for (int e = e0 + t; e < e1; e += 1024) atomicAdd(&cnt[recs[e] >> 17], 1u);
    __syncthreads();
    if (t < NPB) {
        unsigned c = cnt[t];
        unsigned inc = c;
        int lane = t & 63, w = t >> 6;
#pragma unroll
        for (int d = 1; d < 64; d <<= 1) {
            unsigned o = __shfl_up(inc, d, 64);
            if (lane >= d) inc += o;
        }
        if (lane == 63) wtot[w] = inc;
        __syncthreads();
        unsigned wbase = 0;
        for (int i = 0; i < w; ++i) wbase += wtot[i];
        unsigned ex = wbase + inc - c;
        curs[t] = (unsigned)e0 + ex;
        int node = b * NPB + t;
        if (node < n) {
            noff[node] = e0 + (int)ex;
            dinv[node] = rsqrtf((float)c + 1.0f);
        }
    } else {
        __syncthreads();
    }
    if (b == (int)gridDim.x - 1 && t == 0) noff[n] = E;
    __syncthreads();
    for (int e = e0 + t; e < e1; e += 1024) {
        unsigned rec = recs[e];
        unsigned pos = atomicAdd(&curs[rec >> 17], 1u);
        srcs[pos] = rec & 0x1FFFFu;
    }
}

// h[i,:] = (x[i,:] @ W) * dinv[i]  — 64 nodes/block, 4 lanes/node, float4
__global__ void linear_kernel(const float* __restrict__ in, const float* __restrict__ dinv,
                              const float* __restrict__ W, float* __restrict__ out, int n) {
    __shared__ float Ws[F * F];
    __shared__ float As[64][F + 1];
    int t = threadIdx.x;
    Ws[t] = W[t];
    int g = t >> 2, c = t & 3;
    int node = blockIdx.x * 64 + g;
    float4 v = {0.f, 0.f, 0.f, 0.f};
    if (node < n) v = ((const float4*)in)[(size_t)node * 4 + c];
    As[g][c * 4 + 0] = v.x; As[g][c * 4 + 1] = v.y;
    As[g][c * 4 + 2] = v.z; As[g][c * 4 + 3] = v.w;
    __syncthreads();
    if (node < n) {
        float di = dinv[node];
        float4 o = {0.f, 0.f, 0.f, 0.f};
        int j = c * 4;
#pragma unroll
        for (int k = 0; k < F; ++k) {
            float ak = As[g][k];
            o.x += ak * Ws[k * F + j + 0];
            o.y += ak * Ws[k * F + j + 1];
            o.z += ak * Ws[k * F + j + 2];
            o.w += ak * Ws[k * F + j + 3];
        }
        o.x *= di; o.y *= di; o.z *= di; o.w *= di;
        ((float4*)out)[(size_t)node * 4 + c] = o;
    }
}

// atomic-free CSR aggregation — 64 nodes/block, 4 lanes/node, float4 gathers.
// s = sum over in-edges of hin[src,:]; v = dinv*(s + hin[node,:]) + bias
// mode 1: out = (relu(v) @ Wn) * dinv      (mid layer)
// mode 2: out = v                          (final layer)
__global__ void agg_csr_kernel(const float* __restrict__ hin, const unsigned* __restrict__ srcs,
                               const int* __restrict__ noff, const float* __restrict__ dinv,
                               const float* __restrict__ Wn, const float* __restrict__ bias,
                               float* __restrict__ outp, int n, int mode) {
    __shared__ float a1[64][F + 1];
    __shared__ float Ws[F * F];
    int t = threadIdx.x;
    int g = t >> 2, c = t & 3;
    if (mode == 1) Ws[t] = Wn[t];
    int node = blockIdx.x * 64 + g;
    const float4* h4 = (const float4*)hin;
    float4 val = {0.f, 0.f, 0.f, 0.f};
    float di = 0.f;
    if (node < n) {
        di = dinv[node];
        int e0 = noff[node], e1 = noff[node + 1];
        float4 s0 = {0,0,0,0}, s1 = {0,0,0,0}, s2 = {0,0,0,0}, s3 = {0,0,0,0};
        int e = e0;
        for (; e + 4 <= e1; e += 4) {
            int ia = srcs[e], ib = srcs[e + 1], ic = srcs[e + 2], id = srcs[e + 3];
            float4 va = h4[(size_t)ia * 4 + c];
            float4 vb = h4[(size_t)ib * 4 + c];
            float4 vc = h4[(size_t)ic * 4 + c];
            float4 vd = h4[(size_t)id * 4 + c];
            s0.x += va.x; s0.y += va.y; s0.z += va.z; s0.w += va.w;
            s1.x += vb.x; s1.y += vb.y; s1.z += vb.z; s1.w += vb.w;
            s2.x += vc.x; s2.y += vc.y; s2.z += vc.z; s2.w += vc.w;
            s3.x += vd.x; s3.y += vd.y; s3.z += vd.z; s3.w += vd.w;
        }
        for (; e < e1; ++e) {
            float4 va = h4[(size_t)srcs[e] * 4 + c];
            s0.x += va.x; s0.y += va.y; s0.z += va.z; s0.w += va.w;
        }
        float4 self = h4[(size_t)node * 4 + c];
        float4 bi = ((const float4*)bias)[c];
        val.x = di * ((s0.x + s1.x) + (s2.x + s3.x) + self.x) + bi.x;
        val.y = di * ((s0.y + s1.y) + (s2.y + s3.y) + self.y) + bi.y;
        val.z = di * ((s0.z + s1.z) + (s2.z + s3.z) + self.z) + bi.z;
        val.w = di * ((s0.w + s1.w) + (s2.w + s3.w) + self.w) + bi.w;
        if (mode == 1) {
            val.x = fmaxf(val.x, 0.f); val.y = fmaxf(val.y, 0.f);
            val.z = fmaxf(val.z, 0.f); val.w = fmaxf(val.w, 0.f);
        }
    }
    if (mode == 1) {
        a1[g][c * 4 + 0] = val.x; a1[g][c * 4 + 1] = val.y;
        a1[g][c * 4 + 2] = val.z; a1[g][c * 4 + 3] = val.w;
        __syncthreads();
        if (node < n) {
            float4 o = {0.f, 0.f, 0.f, 0.f};
            int j = c * 4;
#pragma unroll
            for (int k = 0; k < F; ++k) {
                float ak = a1[g][k];
                o.x += ak * Ws[k * F + j + 0];
                o.y += ak * Ws[k * F + j + 1];
                o.z += ak * Ws[k * F + j + 2];
                o.w += ak * Ws[k * F + j + 3];
            }
            o.x *= di; o.y *= di; o.z *= di; o.w *= di;
            ((float4*)outp)[(size_t)node * 4 + c] = o;
        }
    } else {
        if (node < n) ((float4*)outp)[(size_t)node * 4 + c] = val;
    }
}

// ========================= fallback (R1) kernels ============================

__global__ void deg_kernel(const int* __restrict__ dst, float* __restrict__ deg, int E) {
    int e = blockIdx.x * blockDim.x + threadIdx.x;
    if (e < E) atomicAdd(&deg[dst[e]], 1.0f);
}
__global__ void dinv_kernel(float* __restrict__ deg, int n) {
    int i = blockIdx.x * blockDim.x + threadIdx.x;
    if (i < n) deg[i] = rsqrtf(deg[i] + 1.0f);
}
__global__ void linear2_kernel(const float* __restrict__ in, const float* __restrict__ acc,
                               const float* __restrict__ dinv, const float* __restrict__ W,
                               const float* __restrict__ bias, float* __restrict__ out,
                               int n, int mode) {
    __shared__ float Ws[F * F];
    __shared__ float As[16][F + 1];
    int t = threadIdx.x;
    Ws[t] = W[t];
    int nb = t >> 4, j = t & 15;
    int i = blockIdx.x * 16 + nb;
    float di = 0.f, v = 0.f;
    if (i < n) {
        di = dinv[i]; v = in[i * F + j];
        if (mode) { v = di * (acc[i * F + j] + v) + bias[j]; v = fmaxf(v, 0.f); }
    }
    As[nb][j] = v;
    __syncthreads();
    if (i < n) {
        float s = 0.f;
#pragma unroll
        for (int k = 0; k < F; ++k) s += As[nb][k] * Ws[k * F + j];
        out[i * F + j] = s * di;
    }
}
__global__ void scatter_kernel(const int* __restrict__ src, const int* __restrict__ dst,
                               const float* __restrict__ h, float* __restrict__ acc, int E) {
    int t = blockIdx.x * blockDim.x + threadIdx.x;
    int e = t >> 4, j = t & 15;
    if (e < E) atomicAdd(&acc[dst[e] * F + j], h[src[e] * F + j]);
}
__global__ void out_kernel(const float* __restrict__ acc, const float* __restrict__ h,
                           const float* __restrict__ dinv, const float* __restrict__ bias,
                           float* __restrict__ out, int n) {
    int t = blockIdx.x * blockDim.x + threadIdx.x;
    if (t < n * F) {
        int i = t >> 4, j = t & 15;
        out[t] = dinv[i] * (acc[t] + h[t]) + bias[j];
    }
}

// ========================= launch ===========================================

extern "C" void kernel_launch(void* const* d_in, const int* in_sizes, int n_in,
                              void* d_out, int out_size, void* d_ws, size_t ws_size,
                              hipStream_t stream) {
    const float* x  = (const float*)d_in[0];
    const int*   ei = (const int*)d_in[1];
    const float* W1 = (const float*)d_in[2];
    const float* b1 = (const float*)d_in[3];
    const float* W2 = (const float*)d_in[4];
    const float* b2 = (const float*)d_in[5];
    float* outp = (float*)d_out;

    const int N = in_sizes[0] / F;
    const int E = in_sizes[1] / 2;
    const int* src = ei;
    const int* dst = ei + E;

    const int nb_rt = (N + NPB - 1) >> BSHIFT;
    // ws layout (4B units): dinv[N] | hA[16N] | hB[16N] | recs[E] | srcs[E] |
    //                       noff[N+1] | bcount[NB] | off[NB+1] | cursor[16*NB]
    size_t need = sizeof(float) * ((size_t)N * 33 + (N + 1)
                                   + 2 * (size_t)E + NB + (NB + 1) + 16 * NB);

    if (nb_rt == NB && ws_size >= need) {
        float* dinv = (float*)d_ws;
        float* hA = dinv + N;
        float* hB = hA + (size_t)F * N;
        unsigned* recs = (unsigned*)(hB + (size_t)F * N);
        unsigned* srcs = recs + E;
        int* noff = (int*)(srcs + E);
        unsigned* bcount = (unsigned*)(noff + N + 1);
        int* off = (int*)(bcount + NB);
        unsigned* cursor = (unsigned*)(off + NB + 1);

        hipMemsetAsync(bcount, 0, NB * sizeof(unsigned), stream);
        hist_kernel<<<512, 256, 0, stream>>>(dst, bcount, E);
        scan_kernel<<<1, 1024, 0, stream>>>(bcount, off, cursor, E);
        reorder_kernel<<<(E + CH - 1) / CH, 512, 0, stream>>>(src, dst, cursor, recs, E);
        sort2_kernel<<<NB, 1024, 0, stream>>>(recs, off, srcs, noff, dinv, N, E);
        linear_kernel<<<(N + 63) / 64, 256, 0, stream>>>(x, dinv, W1, hA, N);
        agg_csr_kernel<<<(N + 63) / 64, 256, 0, stream>>>(hA, srcs, noff, dinv, W2, b1, hB, N, 1);
        agg_csr_kernel<<<(N + 63) / 64, 256, 0, stream>>>(hB, srcs, noff, dinv, nullptr, b2, outp, N, 2);
    } else {
        // R1 fallback: atomic scatter path (13.2MB ws)
        float* dinv = (float*)d_ws;
        float* h = dinv + N;
        float* acc = h + (size_t)F * N;
        hipMemsetAsync(dinv, 0, (size_t)N * sizeof(float), stream);
        hipMemsetAsync(acc, 0, (size_t)F * N * sizeof(float), stream);
        deg_kernel<<<(E + 255) / 256, 256, 0, stream>>>(dst, dinv, E);
        dinv_kernel<<<(N + 255) / 256, 256, 0, stream>>>(dinv, N);
        linear2_kernel<<<(N + 15) / 16, 256, 0, stream>>>(x, nullptr, dinv, W1, nullptr, h, N, 0);
        scatter_kernel<<<((size_t)E * F + 255) / 256, 256, 0, stream>>>(src, dst, h, acc, E);
        linear2_kernel<<<(N + 15) / 16, 256, 0, stream>>>(h, acc, dinv, W2, b1, h, N, 1);
        hipMemsetAsync(acc, 0, (size_t)F * N * sizeof(float), stream);
        scatter_kernel<<<((size_t)E * F + 255) / 256, 256, 0, stream>>>(src, dst, h, acc, E);
        out_kernel<<<((size_t)N * F + 255) / 256, 256, 0, stream>>>(acc, h, dinv, b2, outp, N);
    }
}

// Round 9
// 237.008 us; speedup vs baseline: 1.3674x; 1.0166x over previous
//
#include <hip/hip_runtime.h>

#define F 16
#define BSHIFT 8
#define NPB 256           // nodes per bucket = 1<<BSHIFT
#define NB 391            // buckets for N=100000: ceil(100000/256)
#define CH 4096           // edges per reorder block
#define SCAP 10240        // LDS sort capacity in sort2 (bucket avg ~8184, sd ~90)

// ========================= fast path kernels ================================

// block-privatized histogram of dst>>8 into bcount[NB], int4-vectorized
__global__ void hist_kernel(const int* __restrict__ dst, unsigned* __restrict__ bcount, int E) {
    __shared__ unsigned lc[NB];
    for (int i = threadIdx.x; i < NB; i += blockDim.x) lc[i] = 0;
    __syncthreads();
    int E4 = E >> 2;
    const int4* d4 = (const int4*)dst;
    int stride = gridDim.x * blockDim.x;
    for (int e = blockIdx.x * blockDim.x + threadIdx.x; e < E4; e += stride) {
        int4 v = d4[e];
        atomicAdd(&lc[((unsigned)v.x) >> BSHIFT], 1u);
        atomicAdd(&lc[((unsigned)v.y) >> BSHIFT], 1u);
        atomicAdd(&lc[((unsigned)v.z) >> BSHIFT], 1u);
        atomicAdd(&lc[((unsigned)v.w) >> BSHIFT], 1u);
    }
    for (int e = E4 * 4 + blockIdx.x * blockDim.x + threadIdx.x; e < E; e += stride)
        atomicAdd(&lc[((unsigned)dst[e]) >> BSHIFT], 1u);
    __syncthreads();
    for (int i = threadIdx.x; i < NB; i += blockDim.x) {
        unsigned c = lc[i];
        if (c) atomicAdd(&bcount[i], c);
    }
}

// single-block exclusive scan of NB counts -> off[], cursor[] (cursor padded x16)
__global__ void scan_kernel(const unsigned* __restrict__ bcount, int* __restrict__ off,
                            unsigned* __restrict__ cursor, int E) {
    __shared__ unsigned s[2048];
    int t = threadIdx.x; // 1024 threads
    unsigned c0 = (t < NB) ? bcount[t] : 0u;
    unsigned c1 = (t + 1024 < NB) ? bcount[t + 1024] : 0u;
    s[t] = c0; s[t + 1024] = c1;
    __syncthreads();
    for (int d = 1; d < 2048; d <<= 1) {
        unsigned a  = (t >= d) ? s[t - d] : 0u;
        unsigned bv = (t + 1024 >= d) ? s[t + 1024 - d] : 0u;
        __syncthreads();
        s[t] += a; s[t + 1024] += bv;
        __syncthreads();
    }
    if (t < NB)       { unsigned ex = s[t] - c0;       off[t] = ex;       cursor[t * 16] = ex; }
    if (t + 1024 < NB){ unsigned ex = s[t+1024] - c1;  off[t+1024] = ex;  cursor[(t+1024)*16] = ex; }
    if (t == 0) off[NB] = E;
}

// bucket reorder, LDS counting-sort per 4096-edge chunk. 512 threads/block.
// LDS ~21KB. rec = src | (dst&255)<<17
__global__ __launch_bounds__(512) void
reorder_kernel(const int* __restrict__ src, const int* __restrict__ dst,
               unsigned* __restrict__ cursor, unsigned* __restrict__ recs, int E) {
    __shared__ unsigned lsorted[CH];
    __shared__ unsigned lstart[NB + 1];
    __shared__ unsigned lcur[NB];
    __shared__ int ldelta[NB];
    int t = threadIdx.x, b = blockIdx.x;
    int e0 = b * CH;
    int cnt_e = E - e0; if (cnt_e > CH) cnt_e = CH;
    int i4 = cnt_e >> 2;
    const int4* dst4 = (const int4*)(dst + e0);
    const int4* src4 = (const int4*)(src + e0);

    for (int i = t; i < NB; i += 512) lcur[i] = 0;   // lcur = counts for now
    __syncthreads();
    // phase 1: histogram (int4 coalesced)
    for (int i = t; i < i4; i += 512) {
        int4 d = dst4[i];
        atomicAdd(&lcur[((unsigned)d.x) >> BSHIFT], 1u);
        atomicAdd(&lcur[((unsigned)d.y) >> BSHIFT], 1u);
        atomicAdd(&lcur[((unsigned)d.z) >> BSHIFT], 1u);
        atomicAdd(&lcur[((unsigned)d.w) >> BSHIFT], 1u);
    }
    for (int i = i4 * 4 + t; i < cnt_e; i += 512)
        atomicAdd(&lcur[((unsigned)dst[e0 + i]) >> BSHIFT], 1u);
    __syncthreads();
    // phase 2: exclusive scan of NB counts by wave 0
    if (t < 64) {
        unsigned run = 0;
        for (int c = 0; c < NB; c += 64) {
            int idx = c + t;
            unsigned v = (idx < NB) ? lcur[idx] : 0u;
            unsigned inc = v;
#pragma unroll
            for (int d = 1; d < 64; d <<= 1) {
                unsigned o = __shfl_up(inc, d, 64);
                if (t >= d) inc += o;
            }
            if (idx < NB) lstart[idx] = run + inc - v;
            run += __shfl(inc, 63, 64);
        }
        if (t == 0) lstart[NB] = (unsigned)cnt_e;
    }
    __syncthreads();
    // phase 3: reserve global ranges, init scatter cursors
    for (int i = t; i < NB; i += 512) {
        unsigned st = lstart[i];
        unsigned cnt = lstart[i + 1] - st;
        lcur[i] = st;
        if (cnt) {
            unsigned g = atomicAdd(&cursor[i * 16], cnt);
            ldelta[i] = (int)g - (int)st;
        }
    }
    __syncthreads();
    // phase 4: LDS scatter into sorted order (int4 reads)
    for (int i = t; i < i4; i += 512) {
        int4 d = dst4[i];
        int4 s = src4[i];
        unsigned dd, bk, pos;
        dd = (unsigned)d.x; bk = dd >> BSHIFT; pos = atomicAdd(&lcur[bk], 1u);
        lsorted[pos] = (unsigned)s.x | ((dd & (NPB - 1u)) << 17);
        dd = (unsigned)d.y; bk = dd >> BSHIFT; pos = atomicAdd(&lcur[bk], 1u);
        lsorted[pos] = (unsigned)s.y | ((dd & (NPB - 1u)) << 17);
        dd = (unsigned)d.z; bk = dd >> BSHIFT; pos = atomicAdd(&lcur[bk], 1u);
        lsorted[pos] = (unsigned)s.z | ((dd & (NPB - 1u)) << 17);
        dd = (unsigned)d.w; bk = dd >> BSHIFT; pos = atomicAdd(&lcur[bk], 1u);
        lsorted[pos] = (unsigned)s.w | ((dd & (NPB - 1u)) << 17);
    }
    for (int i = i4 * 4 + t; i < cnt_e; i += 512) {
        unsigned dd = (unsigned)dst[e0 + i];
        unsigned bk = dd >> BSHIFT;
        unsigned pos = atomicAdd(&lcur[bk], 1u);
        lsorted[pos] = (unsigned)src[e0 + i] | ((dd & (NPB - 1u)) << 17);
    }
    __syncthreads();
    // phase 5: run-contiguous write-out; bucket of slot i via binary search in lstart
    for (int i = t; i < cnt_e; i += 512) {
        int lo = 0, hi = NB;   // lstart[lo] <= i < lstart[hi]
        while (hi - lo > 1) {
            int m = (lo + hi) >> 1;
            if (lstart[m] <= (unsigned)i) lo = m; else hi = m;
        }
        recs[ldelta[lo] + i] = lsorted[i];
    }
}

// per-bucket node-granularity sort via LDS counting-sort; COALESCED srcs writes.
// Also emits CSR offsets noff[] and dinv[]. 1024 threads, LDS ~42KB.
__global__ __launch_bounds__(1024) void
sort2_kernel(const unsigned* __restrict__ recs, const int* __restrict__ off,
             unsigned* __restrict__ srcs, int* __restrict__ noff,
             float* __restrict__ dinv, int n, int E) {
    __shared__ unsigned cnt[NPB];
    __shared__ unsigned curs[NPB];
    __shared__ unsigned lsort[SCAP];
    __shared__ unsigned wtot[4];
    int t = threadIdx.x, b = blockIdx.x;
    if (t < NPB) cnt[t] = 0;
    __syncthreads();
    int e0 = off[b], e1 = off[b + 1];
    int cnt_e = e1 - e0;
    for (int e = e0 + t; e < e1; e += 1024) atomicAdd(&cnt[recs[e] >> 17], 1u);
    __syncthreads();
    if (t < NPB) {
        unsigned c = cnt[t];
        unsigned inc = c;
        int lane = t & 63, w = t >> 6;
#pragma unroll
        for (int d = 1; d < 64; d <<= 1) {
            unsigned o = __shfl_up(inc, d, 64);
            if (lane >= d) inc += o;
        }
        if (lane == 63) wtot[w] = inc;
        __syncthreads();
        unsigned wbase = 0;
        for (int i = 0; i < w; ++i) wbase += wtot[i];
        unsigned ex = wbase + inc - c;          // exclusive scan within bucket
        curs[t] = ex;
        int node = b * NPB + t;
        if (node < n) {
            noff[node] = e0 + (int)ex;
            dinv[node] = rsqrtf((float)c + 1.0f);
        }
    } else {
        __syncthreads();
    }
    if (b == (int)gridDim.x - 1 && t == 0) noff[n] = E;
    __syncthreads();
    // LDS scatter into node-sorted order (positions local to bucket)
    for (int e = e0 + t; e < e1; e += 1024) {
        unsigned rec = recs[e];
        unsigned pos = atomicAdd(&curs[rec >> 17], 1u);
        if (pos < SCAP) lsort[pos] = rec & 0x1FFFFu;
        else srcs[e0 + pos] = rec & 0x1FFFFu;    // overflow guard (statistically never)
    }
    __syncthreads();
    // coalesced write-out
    int m = cnt_e < SCAP ? cnt_e : SCAP;
    for (int i = t; i < m; i += 1024) srcs[e0 + i] = lsort[i];
}

// h[i,:] = (x[i,:] @ W) * dinv[i]  — 64 nodes/block, 4 lanes/node, float4
__global__ void linear_kernel(const float* __restrict__ in, const float* __restrict__ dinv,
                              const float* __restrict__ W, float* __restrict__ out, int n) {
    __shared__ float Ws[F * F];
    __shared__ float As[64][F + 1];
    int t = threadIdx.x;
    Ws[t] = W[t];
    int g = t >> 2, c = t & 3;
    int node = blockIdx.x * 64 + g;
    float4 v = {0.f, 0.f, 0.f, 0.f};
    if (node < n) v = ((const float4*)in)[(size_t)node * 4 + c];
    As[g][c * 4 + 0] = v.x; As[g][c * 4 + 1] = v.y;
    As[g][c * 4 + 2] = v.z; As[g][c * 4 + 3] = v.w;
    __syncthreads();
    if (node < n) {
        float di = dinv[node];
        float4 o = {0.f, 0.f, 0.f, 0.f};
        int j = c * 4;
#pragma unroll
        for (int k = 0; k < F; ++k) {
            float ak = As[g][k];
            o.x += ak * Ws[k * F + j + 0];
            o.y += ak * Ws[k * F + j + 1];
            o.z += ak * Ws[k * F + j + 2];
            o.w += ak * Ws[k * F + j + 3];
        }
        o.x *= di; o.y *= di; o.z *= di; o.w *= di;
        ((float4*)out)[(size_t)node * 4 + c] = o;
    }
}

// atomic-free CSR aggregation — 64 nodes/block, 4 lanes/node, float4 gathers.
// s = sum over in-edges of hin[src,:]; v = dinv*(s + hin[node,:]) + bias
// mode 1: out = (relu(v) @ Wn) * dinv      (mid layer)
// mode 2: out = v                          (final layer)
__global__ void agg_csr_kernel(const float* __restrict__ hin, const unsigned* __restrict__ srcs,
                               const int* __restrict__ noff, const float* __restrict__ dinv,
                               const float* __restrict__ Wn, const float* __restrict__ bias,
                               float* __restrict__ outp, int n, int mode) {
    __shared__ float a1[64][F + 1];
    __shared__ float Ws[F * F];
    int t = threadIdx.x;
    int g = t >> 2, c = t & 3;
    if (mode == 1) Ws[t] = Wn[t];
    int node = blockIdx.x * 64 + g;
    const float4* h4 = (const float4*)hin;
    float4 val = {0.f, 0.f, 0.f, 0.f};
    float di = 0.f;
    if (node < n) {
        di = dinv[node];
        int e0 = noff[node], e1 = noff[node + 1];
        float4 s0 = {0,0,0,0}, s1 = {0,0,0,0}, s2 = {0,0,0,0}, s3 = {0,0,0,0};
        int e = e0;
        for (; e + 4 <= e1; e += 4) {
            int ia = srcs[e], ib = srcs[e + 1], ic = srcs[e + 2], id = srcs[e + 3];
            float4 va = h4[(size_t)ia * 4 + c];
            float4 vb = h4[(size_t)ib * 4 + c];
            float4 vc = h4[(size_t)ic * 4 + c];
            float4 vd = h4[(size_t)id * 4 + c];
            s0.x += va.x; s0.y += va.y; s0.z += va.z; s0.w += va.w;
            s1.x += vb.x; s1.y += vb.y; s1.z += vb.z; s1.w += vb.w;
            s2.x += vc.x; s2.y += vc.y; s2.z += vc.z; s2.w += vc.w;
            s3.x += vd.x; s3.y += vd.y; s3.z += vd.z; s3.w += vd.w;
        }
        for (; e < e1; ++e) {
            float4 va = h4[(size_t)srcs[e] * 4 + c];
            s0.x += va.x; s0.y += va.y; s0.z += va.z; s0.w += va.w;
        }
        float4 self = h4[(size_t)node * 4 + c];
        float4 bi = ((const float4*)bias)[c];
        val.x = di * ((s0.x + s1.x) + (s2.x + s3.x) + self.x) + bi.x;
        val.y = di * ((s0.y + s1.y) + (s2.y + s3.y) + self.y) + bi.y;
        val.z = di * ((s0.z + s1.z) + (s2.z + s3.z) + self.z) + bi.z;
        val.w = di * ((s0.w + s1.w) + (s2.w + s3.w) + self.w) + bi.w;
        if (mode == 1) {
            val.x = fmaxf(val.x, 0.f); val.y = fmaxf(val.y, 0.f);
            val.z = fmaxf(val.z, 0.f); val.w = fmaxf(val.w, 0.f);
        }
    }
    if (mode == 1) {
        a1[g][c * 4 + 0] = val.x; a1[g][c * 4 + 1] = val.y;
        a1[g][c * 4 + 2] = val.z; a1[g][c * 4 + 3] = val.w;
        __syncthreads();
        if (node < n) {
            float4 o = {0.f, 0.f, 0.f, 0.f};
            int j = c * 4;
#pragma unroll
            for (int k = 0; k < F; ++k) {
                float ak = a1[g][k];
                o.x += ak * Ws[k * F + j + 0];
                o.y += ak * Ws[k * F + j + 1];
                o.z += ak * Ws[k * F + j + 2];
                o.w += ak * Ws[k * F + j + 3];
            }
            o.x *= di; o.y *= di; o.z *= di; o.w *= di;
            ((float4*)outp)[(size_t)node * 4 + c] = o;
        }
    } else {
        if (node < n) ((float4*)outp)[(size_t)node * 4 + c] = val;
    }
}

// ========================= fallback (R1) kernels ============================

__global__ void deg_kernel(const int* __restrict__ dst, float* __restrict__ deg, int E) {
    int e = blockIdx.x * blockDim.x + threadIdx.x;
    if (e < E) atomicAdd(&deg[dst[e]], 1.0f);
}
__global__ void dinv_kernel(float* __restrict__ deg, int n) {
    int i = blockIdx.x * blockDim.x + threadIdx.x;
    if (i < n) deg[i] = rsqrtf(deg[i] + 1.0f);
}
__global__ void linear2_kernel(const float* __restrict__ in, const float* __restrict__ acc,
                               const float* __restrict__ dinv, const float* __restrict__ W,
                               const float* __restrict__ bias, float* __restrict__ out,
                               int n, int mode) {
    __shared__ float Ws[F * F];
    __shared__ float As[16][F + 1];
    int t = threadIdx.x;
    Ws[t] = W[t];
    int nb = t >> 4, j = t & 15;
    int i = blockIdx.x * 16 + nb;
    float di = 0.f, v = 0.f;
    if (i < n) {
        di = dinv[i]; v = in[i * F + j];
        if (mode) { v = di * (acc[i * F + j] + v) + bias[j]; v = fmaxf(v, 0.f); }
    }
    As[nb][j] = v;
    __syncthreads();
    if (i < n) {
        float s = 0.f;
#pragma unroll
        for (int k = 0; k < F; ++k) s += As[nb][k] * Ws[k * F + j];
        out[i * F + j] = s * di;
    }
}
__global__ void scatter_kernel(const int* __restrict__ src, const int* __restrict__ dst,
                               const float* __restrict__ h, float* __restrict__ acc, int E) {
    int t = blockIdx.x * blockDim.x + threadIdx.x;
    int e = t >> 4, j = t & 15;
    if (e < E) atomicAdd(&acc[dst[e] * F + j], h[src[e] * F + j]);
}
__global__ void out_kernel(const float* __restrict__ acc, const float* __restrict__ h,
                           const float* __restrict__ dinv, const float* __restrict__ bias,
                           float* __restrict__ out, int n) {
    int t = blockIdx.x * blockDim.x + threadIdx.x;
    if (t < n * F) {
        int i = t >> 4, j = t & 15;
        out[t] = dinv[i] * (acc[t] + h[t]) + bias[j];
    }
}

// ========================= launch ===========================================

extern "C" void kernel_launch(void* const* d_in, const int* in_sizes, int n_in,
                              void* d_out, int out_size, void* d_ws, size_t ws_size,
                              hipStream_t stream) {
    const float* x  = (const float*)d_in[0];
    const int*   ei = (const int*)d_in[1];
    const float* W1 = (const float*)d_in[2];
    const float* b1 = (const float*)d_in[3];
    const float* W2 = (const float*)d_in[4];
    const float* b2 = (const float*)d_in[5];
    float* outp = (float*)d_out;

    const int N = in_sizes[0] / F;
    const int E = in_sizes[1] / 2;
    const int* src = ei;
    const int* dst = ei + E;

    const int nb_rt = (N + NPB - 1) >> BSHIFT;
    // ws layout (4B units): dinv[N] | hA[16N] | hB[16N] | recs[E] | srcs[E] |
    //                       noff[N+1] | bcount[NB] | off[NB+1] | cursor[16*NB]
    size_t need = sizeof(float) * ((size_t)N * 33 + (N + 1)
                                   + 2 * (size_t)E + NB + (NB + 1) + 16 * NB);

    if (nb_rt == NB && ws_size >= need) {
        float* dinv = (float*)d_ws;
        float* hA = dinv + N;
        float* hB = hA + (size_t)F * N;
        unsigned* recs = (unsigned*)(hB + (size_t)F * N);
        unsigned* srcs = recs + E;
        int* noff = (int*)(srcs + E);
        unsigned* bcount = (unsigned*)(noff + N + 1);
        int* off = (int*)(bcount + NB);
        unsigned* cursor = (unsigned*)(off + NB + 1);

        hipMemsetAsync(bcount, 0, NB * sizeof(unsigned), stream);
        hist_kernel<<<512, 256, 0, stream>>>(dst, bcount, E);
        scan_kernel<<<1, 1024, 0, stream>>>(bcount, off, cursor, E);
        reorder_kernel<<<(E + CH - 1) / CH, 512, 0, stream>>>(src, dst, cursor, recs, E);
        sort2_kernel<<<NB, 1024, 0, stream>>>(recs, off, srcs, noff, dinv, N, E);
        linear_kernel<<<(N + 63) / 64, 256, 0, stream>>>(x, dinv, W1, hA, N);
        agg_csr_kernel<<<(N + 63) / 64, 256, 0, stream>>>(hA, srcs, noff, dinv, W2, b1, hB, N, 1);
        agg_csr_kernel<<<(N + 63) / 64, 256, 0, stream>>>(hB, srcs, noff, dinv, nullptr, b2, outp, N, 2);
    } else {
        // R1 fallback: atomic scatter path (13.2MB ws)
        float* dinv = (float*)d_ws;
        float* h = dinv + N;
        float* acc = h + (size_t)F * N;
        hipMemsetAsync(dinv, 0, (size_t)N * sizeof(float), stream);
        hipMemsetAsync(acc, 0, (size_t)F * N * sizeof(float), stream);
        deg_kernel<<<(E + 255) / 256, 256, 0, stream>>>(dst, dinv, E);
        dinv_kernel<<<(N + 255) / 256, 256, 0, stream>>>(dinv, N);
        linear2_kernel<<<(N + 15) / 16, 256, 0, stream>>>(x, nullptr, dinv, W1, nullptr, h, N, 0);
        scatter_kernel<<<((size_t)E * F + 255) / 256, 256, 0, stream>>>(src, dst, h, acc, E);
        linear2_kernel<<<(N + 15) / 16, 256, 0, stream>>>(h, acc, dinv, W2, b1, h, N, 1);
        hipMemsetAsync(acc, 0, (size_t)F * N * sizeof(float), stream);
        scatter_kernel<<<((size_t)E * F + 255) / 256, 256, 0, stream>>>(src, dst, h, acc, E);
        out_kernel<<<((size_t)N * F + 255) / 256, 256, 0, stream>>>(acc, h, dinv, b2, outp, N);
    }
}

// Round 10
// 214.110 us; speedup vs baseline: 1.5136x; 1.1069x over previous
//
#include <hip/hip_runtime.h>

#define F 16
#define BSHIFT 8
#define NPB 256           // nodes per bucket
#define NB 391            // buckets for N=100000
#define CH 4096           // edges per reorder block
#define BCAP 9216         // padded per-bucket edge capacity (mean 8184, sd ~90)

// ========================= fast path kernels ================================

__global__ void init_cursor_kernel(unsigned* __restrict__ cursor) {
    int i = threadIdx.x;
    if (i < NB) cursor[i * 16] = (unsigned)(i * BCAP);
}

// bucket reorder via rank-trick counting sort. 512 threads, 1 LDS-atomic pass.
// rec = src | (dst&255)<<17 ; output arena: bucket k occupies [k*BCAP, ...)
__global__ __launch_bounds__(512) void
reorder_kernel(const int* __restrict__ src, const int* __restrict__ dst,
               unsigned* __restrict__ cursor, unsigned* __restrict__ recs, int E) {
    __shared__ unsigned lsorted[CH];
    __shared__ unsigned short lbkt[CH];
    __shared__ unsigned cnt[NB];       // counts; later reused as global run base
    __shared__ unsigned lstart[NB + 1];
    int t = threadIdx.x, b = blockIdx.x;
    int e0 = b * CH;
    int cnt_e = E - e0; if (cnt_e > CH) cnt_e = CH;

    for (int i = t; i < NB; i += 512) cnt[i] = 0;
    __syncthreads();
    // phase 1: histogram + per-edge rank kept in registers
    unsigned pk[8];
#pragma unroll
    for (int j = 0; j < 8; ++j) {
        int i = t + j * 512;
        pk[j] = 0xFFFFFFFFu;
        if (i < cnt_e) {
            unsigned d = (unsigned)dst[e0 + i];
            unsigned bk = d >> BSHIFT;
            unsigned r = atomicAdd(&cnt[bk], 1u);
            pk[j] = bk | ((d & 255u) << 9) | (r << 17);   // bk:9 | low:8 | rank:<=12
        }
    }
    __syncthreads();
    // phase 2: exclusive scan of NB counts by wave 0
    if (t < 64) {
        unsigned run = 0;
        for (int c = 0; c < NB; c += 64) {
            int idx = c + t;
            unsigned v = (idx < NB) ? cnt[idx] : 0u;
            unsigned inc = v;
#pragma unroll
            for (int d = 1; d < 64; d <<= 1) {
                unsigned o = __shfl_up(inc, d, 64);
                if (t >= d) inc += o;
            }
            if (idx < NB) lstart[idx] = run + inc - v;
            run += __shfl(inc, 63, 64);
        }
        if (t == 0) lstart[NB] = (unsigned)cnt_e;
    }
    __syncthreads();
    // phase 3: reserve global run per touched bucket; cnt[i] becomes global base
    for (int i = t; i < NB; i += 512) {
        unsigned c = cnt[i];
        if (c) cnt[i] = atomicAdd(&cursor[i * 16], c);
    }
    __syncthreads();
    // phase 4: non-atomic LDS scatter using saved ranks (re-read src coalesced)
#pragma unroll
    for (int j = 0; j < 8; ++j) {
        int i = t + j * 512;
        if (i < cnt_e) {
            unsigned p = pk[j];
            unsigned bk = p & 0x1FFu;
            unsigned low = (p >> 9) & 255u;
            unsigned r = p >> 17;
            unsigned pos = lstart[bk] + r;
            lsorted[pos] = (unsigned)src[e0 + i] | (low << 17);
            lbkt[pos] = (unsigned short)bk;
        }
    }
    __syncthreads();
    // phase 5: run-contiguous global write-out
    for (int i = t; i < cnt_e; i += 512) {
        unsigned bk = lbkt[i];
        recs[cnt[bk] + ((unsigned)i - lstart[bk])] = lsorted[i];
    }
}

// per-bucket node sort via rank-trick; coalesced srcs writes; emits noff/nend/dinv.
__global__ __launch_bounds__(1024) void
sort2_kernel(const unsigned* __restrict__ recs, const unsigned* __restrict__ cursor,
             unsigned* __restrict__ srcs, int* __restrict__ noff, int* __restrict__ nend,
             float* __restrict__ dinv, int n) {
    __shared__ unsigned lsort[BCAP];
    __shared__ unsigned cnt[NPB];
    __shared__ unsigned ex[NPB];
    __shared__ unsigned wtot[4];
    int t = threadIdx.x, b = blockIdx.x;
    int e0 = b * BCAP;
    int used = (int)(cursor[b * 16] - (unsigned)e0);
    if (t < NPB) cnt[t] = 0;
    __syncthreads();
    // phase 1: per-node histogram + ranks in registers
    unsigned pk[9];
#pragma unroll
    for (int j = 0; j < 9; ++j) {
        int i = t + j * 1024;
        pk[j] = 0xFFFFFFFFu;
        if (i < used) {
            unsigned node = recs[e0 + i] >> 17;
            unsigned r = atomicAdd(&cnt[node], 1u);
            pk[j] = node | (r << 8);
        }
    }
    __syncthreads();
    // phase 2: 256-entry exclusive scan (4 waves) + CSR/dinv emit
    if (t < NPB) {
        unsigned c = cnt[t];
        unsigned inc = c;
        int lane = t & 63, w = t >> 6;
#pragma unroll
        for (int d = 1; d < 64; d <<= 1) {
            unsigned o = __shfl_up(inc, d, 64);
            if (lane >= d) inc += o;
        }
        if (lane == 63) wtot[w] = inc;
        __syncthreads();
        unsigned wbase = 0;
        for (int i = 0; i < w; ++i) wbase += wtot[i];
        unsigned e = wbase + inc - c;
        ex[t] = e;
        int node = b * NPB + t;
        if (node < n) {
            noff[node] = e0 + (int)e;
            nend[node] = e0 + (int)(e + c);
            dinv[node] = rsqrtf((float)c + 1.0f);
        }
    } else {
        __syncthreads();
    }
    __syncthreads();
    // phase 3: non-atomic LDS scatter (re-read recs, L2-hot)
#pragma unroll
    for (int j = 0; j < 9; ++j) {
        int i = t + j * 1024;
        if (i < used) {
            unsigned p = pk[j];
            lsort[ex[p & 255u] + (p >> 8)] = recs[e0 + i] & 0x1FFFFu;
        }
    }
    __syncthreads();
    // phase 4: coalesced write-out
    for (int i = t; i < used; i += 1024) srcs[e0 + i] = lsort[i];
}

// h[i,:] = (x[i,:] @ W) * dinv[i]  — 64 nodes/block, 4 lanes/node, float4
__global__ void linear_kernel(const float* __restrict__ in, const float* __restrict__ dinv,
                              const float* __restrict__ W, float* __restrict__ out, int n) {
    __shared__ float Ws[F * F];
    __shared__ float As[64][F + 1];
    int t = threadIdx.x;
    Ws[t] = W[t];
    int g = t >> 2, c = t & 3;
    int node = blockIdx.x * 64 + g;
    float4 v = {0.f, 0.f, 0.f, 0.f};
    if (node < n) v = ((const float4*)in)[(size_t)node * 4 + c];
    As[g][c * 4 + 0] = v.x; As[g][c * 4 + 1] = v.y;
    As[g][c * 4 + 2] = v.z; As[g][c * 4 + 3] = v.w;
    __syncthreads();
    if (node < n) {
        float di = dinv[node];
        float4 o = {0.f, 0.f, 0.f, 0.f};
        int j = c * 4;
#pragma unroll
        for (int k = 0; k < F; ++k) {
            float ak = As[g][k];
            o.x += ak * Ws[k * F + j + 0];
            o.y += ak * Ws[k * F + j + 1];
            o.z += ak * Ws[k * F + j + 2];
            o.w += ak * Ws[k * F + j + 3];
        }
        o.x *= di; o.y *= di; o.z *= di; o.w *= di;
        ((float4*)out)[(size_t)node * 4 + c] = o;
    }
}

// atomic-free CSR aggregation — 64 nodes/block, 4 lanes/node, float4 gathers.
// mode 1: out = (relu(v) @ Wn) * dinv ; mode 2: out = v
__global__ void agg_csr_kernel(const float* __restrict__ hin, const unsigned* __restrict__ srcs,
                               const int* __restrict__ noff, const int* __restrict__ nend,
                               const float* __restrict__ dinv,
                               const float* __restrict__ Wn, const float* __restrict__ bias,
                               float* __restrict__ outp, int n, int mode) {
    __shared__ float a1[64][F + 1];
    __shared__ float Ws[F * F];
    int t = threadIdx.x;
    int g = t >> 2, c = t & 3;
    if (mode == 1) Ws[t] = Wn[t];
    int node = blockIdx.x * 64 + g;
    const float4* h4 = (const float4*)hin;
    float4 val = {0.f, 0.f, 0.f, 0.f};
    float di = 0.f;
    if (node < n) {
        di = dinv[node];
        int e0 = noff[node], e1 = nend[node];
        float4 s0 = {0,0,0,0}, s1 = {0,0,0,0}, s2 = {0,0,0,0}, s3 = {0,0,0,0};
        int e = e0;
        for (; e + 4 <= e1; e += 4) {
            int ia = srcs[e], ib = srcs[e + 1], ic = srcs[e + 2], id = srcs[e + 3];
            float4 va = h4[(size_t)ia * 4 + c];
            float4 vb = h4[(size_t)ib * 4 + c];
            float4 vc = h4[(size_t)ic * 4 + c];
            float4 vd = h4[(size_t)id * 4 + c];
            s0.x += va.x; s0.y += va.y; s0.z += va.z; s0.w += va.w;
            s1.x += vb.x; s1.y += vb.y; s1.z += vb.z; s1.w += vb.w;
            s2.x += vc.x; s2.y += vc.y; s2.z += vc.z; s2.w += vc.w;
            s3.x += vd.x; s3.y += vd.y; s3.z += vd.z; s3.w += vd.w;
        }
        for (; e < e1; ++e) {
            float4 va = h4[(size_t)srcs[e] * 4 + c];
            s0.x += va.x; s0.y += va.y; s0.z += va.z; s0.w += va.w;
        }
        float4 self = h4[(size_t)node * 4 + c];
        float4 bi = ((const float4*)bias)[c];
        val.x = di * ((s0.x + s1.x) + (s2.x + s3.x) + self.x) + bi.x;
        val.y = di * ((s0.y + s1.y) + (s2.y + s3.y) + self.y) + bi.y;
        val.z = di * ((s0.z + s1.z) + (s2.z + s3.z) + self.z) + bi.z;
        val.w = di * ((s0.w + s1.w) + (s2.w + s3.w) + self.w) + bi.w;
        if (mode == 1) {
            val.x = fmaxf(val.x, 0.f); val.y = fmaxf(val.y, 0.f);
            val.z = fmaxf(val.z, 0.f); val.w = fmaxf(val.w, 0.f);
        }
    }
    if (mode == 1) {
        a1[g][c * 4 + 0] = val.x; a1[g][c * 4 + 1] = val.y;
        a1[g][c * 4 + 2] = val.z; a1[g][c * 4 + 3] = val.w;
        __syncthreads();
        if (node < n) {
            float4 o = {0.f, 0.f, 0.f, 0.f};
            int j = c * 4;
#pragma unroll
            for (int k = 0; k < F; ++k) {
                float ak = a1[g][k];
                o.x += ak * Ws[k * F + j + 0];
                o.y += ak * Ws[k * F + j + 1];
                o.z += ak * Ws[k * F + j + 2];
                o.w += ak * Ws[k * F + j + 3];
            }
            o.x *= di; o.y *= di; o.z *= di; o.w *= di;
            ((float4*)outp)[(size_t)node * 4 + c] = o;
        }
    } else {
        if (node < n) ((float4*)outp)[(size_t)node * 4 + c] = val;
    }
}

// ========================= fallback (R1) kernels ============================

__global__ void deg_kernel(const int* __restrict__ dst, float* __restrict__ deg, int E) {
    int e = blockIdx.x * blockDim.x + threadIdx.x;
    if (e < E) atomicAdd(&deg[dst[e]], 1.0f);
}
__global__ void dinv_kernel(float* __restrict__ deg, int n) {
    int i = blockIdx.x * blockDim.x + threadIdx.x;
    if (i < n) deg[i] = rsqrtf(deg[i] + 1.0f);
}
__global__ void linear2_kernel(const float* __restrict__ in, const float* __restrict__ acc,
                               const float* __restrict__ dinv, const float* __restrict__ W,
                               const float* __restrict__ bias, float* __restrict__ out,
                               int n, int mode) {
    __shared__ float Ws[F * F];
    __shared__ float As[16][F + 1];
    int t = threadIdx.x;
    Ws[t] = W[t];
    int nb = t >> 4, j = t & 15;
    int i = blockIdx.x * 16 + nb;
    float di = 0.f, v = 0.f;
    if (i < n) {
        di = dinv[i]; v = in[i * F + j];
        if (mode) { v = di * (acc[i * F + j] + v) + bias[j]; v = fmaxf(v, 0.f); }
    }
    As[nb][j] = v;
    __syncthreads();
    if (i < n) {
        float s = 0.f;
#pragma unroll
        for (int k = 0; k < F; ++k) s += As[nb][k] * Ws[k * F + j];
        out[i * F + j] = s * di;
    }
}
__global__ void scatter_kernel(const int* __restrict__ src, const int* __restrict__ dst,
                               const float* __restrict__ h, float* __restrict__ acc, int E) {
    int t = blockIdx.x * blockDim.x + threadIdx.x;
    int e = t >> 4, j = t & 15;
    if (e < E) atomicAdd(&acc[dst[e] * F + j], h[src[e] * F + j]);
}
__global__ void out_kernel(const float* __restrict__ acc, const float* __restrict__ h,
                           const float* __restrict__ dinv, const float* __restrict__ bias,
                           float* __restrict__ out, int n) {
    int t = blockIdx.x * blockDim.x + threadIdx.x;
    if (t < n * F) {
        int i = t >> 4, j = t & 15;
        out[t] = dinv[i] * (acc[t] + h[t]) + bias[j];
    }
}

// ========================= launch ===========================================

extern "C" void kernel_launch(void* const* d_in, const int* in_sizes, int n_in,
                              void* d_out, int out_size, void* d_ws, size_t ws_size,
                              hipStream_t stream) {
    const float* x  = (const float*)d_in[0];
    const int*   ei = (const int*)d_in[1];
    const float* W1 = (const float*)d_in[2];
    const float* b1 = (const float*)d_in[3];
    const float* W2 = (const float*)d_in[4];
    const float* b2 = (const float*)d_in[5];
    float* outp = (float*)d_out;

    const int N = in_sizes[0] / F;
    const int E = in_sizes[1] / 2;
    const int* src = ei;
    const int* dst = ei + E;

    const int nb_rt = (N + NPB - 1) >> BSHIFT;
    const size_t RC = (size_t)NB * BCAP;           // 3,603,456 entries (> 16N)
    // ws layout (4B units): dinv[N] | hA[16N] | recs[RC] (hB aliases) | srcs[RC] |
    //                       noff[N] | nend[N] | cursor[16*NB]
    size_t need = sizeof(unsigned) * ((size_t)N * 19 + 2 * RC + 16 * NB);

    if (nb_rt == NB && E <= CH * 65535 && ws_size >= need) {
        float* dinv = (float*)d_ws;
        float* hA = dinv + N;
        unsigned* recs = (unsigned*)(hA + (size_t)F * N);
        float* hB = (float*)recs;                  // alias: recs dead after sort2
        unsigned* srcs = recs + RC;
        int* noff = (int*)(srcs + RC);
        int* nend = noff + N;
        unsigned* cursor = (unsigned*)(nend + N);

        init_cursor_kernel<<<1, 512, 0, stream>>>(cursor);
        reorder_kernel<<<(E + CH - 1) / CH, 512, 0, stream>>>(src, dst, cursor, recs, E);
        sort2_kernel<<<NB, 1024, 0, stream>>>(recs, cursor, srcs, noff, nend, dinv, N);
        linear_kernel<<<(N + 63) / 64, 256, 0, stream>>>(x, dinv, W1, hA, N);
        agg_csr_kernel<<<(N + 63) / 64, 256, 0, stream>>>(hA, srcs, noff, nend, dinv, W2, b1, hB, N, 1);
        agg_csr_kernel<<<(N + 63) / 64, 256, 0, stream>>>(hB, srcs, noff, nend, dinv, nullptr, b2, outp, N, 2);
    } else {
        // R1 fallback: atomic scatter path (13.2MB ws)
        float* dinv = (float*)d_ws;
        float* h = dinv + N;
        float* acc = h + (size_t)F * N;
        hipMemsetAsync(dinv, 0, (size_t)N * sizeof(float), stream);
        hipMemsetAsync(acc, 0, (size_t)F * N * sizeof(float), stream);
        deg_kernel<<<(E + 255) / 256, 256, 0, stream>>>(dst, dinv, E);
        dinv_kernel<<<(N + 255) / 256, 256, 0, stream>>>(dinv, N);
        linear2_kernel<<<(N + 15) / 16, 256, 0, stream>>>(x, nullptr, dinv, W1, nullptr, h, N, 0);
        scatter_kernel<<<((size_t)E * F + 255) / 256, 256, 0, stream>>>(src, dst, h, acc, E);
        linear2_kernel<<<(N + 15) / 16, 256, 0, stream>>>(h, acc, dinv, W2, b1, h, N, 1);
        hipMemsetAsync(acc, 0, (size_t)F * N * sizeof(float), stream);
        scatter_kernel<<<((size_t)E * F + 255) / 256, 256, 0, stream>>>(src, dst, h, acc, E);
        out_kernel<<<((size_t)N * F + 255) / 256, 256, 0, stream>>>(acc, h, dinv, b2, outp, N);
    }
}

// Round 11
// 206.295 us; speedup vs baseline: 1.5710x; 1.0379x over previous
//
#include <hip/hip_runtime.h>

#define F 16
#define BSHIFT 8
#define NPB 256           // nodes per bucket
#define NB 391            // buckets for N=100000
#define CH 4096           // edges per reorder block
#define BCAP 9216         // padded per-bucket edge capacity (mean 8184, sd ~90)

// ========================= fast path kernels ================================

__global__ void init_cursor_kernel(unsigned* __restrict__ cursor) {
    int i = threadIdx.x;
    if (i < NB) cursor[i * 16] = (unsigned)(i * BCAP);
}

// bucket reorder via rank-trick counting sort. 512 threads, 1 LDS-atomic pass,
// src cached in registers (no re-read). rec = src | (dst&255)<<17
__global__ __launch_bounds__(512) void
reorder_kernel(const int* __restrict__ src, const int* __restrict__ dst,
               unsigned* __restrict__ cursor, unsigned* __restrict__ recs, int E) {
    __shared__ unsigned lsorted[CH];
    __shared__ unsigned short lbkt[CH];
    __shared__ unsigned cnt[NB];       // counts; later reused as global run base
    __shared__ unsigned lstart[NB + 1];
    int t = threadIdx.x, b = blockIdx.x;
    int e0 = b * CH;
    int cnt_e = E - e0; if (cnt_e > CH) cnt_e = CH;

    for (int i = t; i < NB; i += 512) cnt[i] = 0;
    __syncthreads();
    // phase 1: histogram + per-edge (bucket,low,rank) and src kept in registers
    unsigned pk[8], rs[8];
#pragma unroll
    for (int j = 0; j < 8; ++j) {
        int i = t + j * 512;
        pk[j] = 0xFFFFFFFFu;
        if (i < cnt_e) {
            unsigned d = (unsigned)dst[e0 + i];
            rs[j] = (unsigned)src[e0 + i];
            unsigned bk = d >> BSHIFT;
            unsigned r = atomicAdd(&cnt[bk], 1u);
            pk[j] = bk | ((d & 255u) << 9) | (r << 17);   // bk:9 | low:8 | rank:12
        }
    }
    __syncthreads();
    // phase 2: exclusive scan of NB counts by wave 0
    if (t < 64) {
        unsigned run = 0;
        for (int c = 0; c < NB; c += 64) {
            int idx = c + t;
            unsigned v = (idx < NB) ? cnt[idx] : 0u;
            unsigned inc = v;
#pragma unroll
            for (int d = 1; d < 64; d <<= 1) {
                unsigned o = __shfl_up(inc, d, 64);
                if (t >= d) inc += o;
            }
            if (idx < NB) lstart[idx] = run + inc - v;
            run += __shfl(inc, 63, 64);
        }
        if (t == 0) lstart[NB] = (unsigned)cnt_e;
    }
    __syncthreads();
    // phase 3: reserve global run per touched bucket; cnt[i] becomes global base
    for (int i = t; i < NB; i += 512) {
        unsigned c = cnt[i];
        if (c) cnt[i] = atomicAdd(&cursor[i * 16], c);
    }
    __syncthreads();
    // phase 4: non-atomic LDS scatter from registers
#pragma unroll
    for (int j = 0; j < 8; ++j) {
        int i = t + j * 512;
        if (i < cnt_e) {
            unsigned p = pk[j];
            unsigned bk = p & 0x1FFu;
            unsigned pos = lstart[bk] + (p >> 17);
            lsorted[pos] = rs[j] | (((p >> 9) & 255u) << 17);
            lbkt[pos] = (unsigned short)bk;
        }
    }
    __syncthreads();
    // phase 5: run-contiguous global write-out
    for (int i = t; i < cnt_e; i += 512) {
        unsigned bk = lbkt[i];
        recs[cnt[bk] + ((unsigned)i - lstart[bk])] = lsorted[i];
    }
}

// per-bucket node sort via rank-trick (recs cached in regs); coalesced srcs
// writes; emits noff/nend/dinv; fused tail computes z = x*dinv for own nodes.
__global__ __launch_bounds__(1024) void
sort2_kernel(const unsigned* __restrict__ recs, const unsigned* __restrict__ cursor,
             unsigned* __restrict__ srcs, int* __restrict__ noff, int* __restrict__ nend,
             float* __restrict__ dinv, const float* __restrict__ x,
             float* __restrict__ z, int n) {
    __shared__ unsigned lsort[BCAP];
    __shared__ unsigned cnt[NPB];
    __shared__ unsigned ex[NPB];
    __shared__ float ldv[NPB];
    __shared__ unsigned wtot[4];
    int t = threadIdx.x, b = blockIdx.x;
    int e0 = b * BCAP;
    int used = (int)(cursor[b * 16] - (unsigned)e0);
    if (t < NPB) cnt[t] = 0;
    __syncthreads();
    // phase 1: per-node histogram + (node,rank) and src kept in registers
    unsigned pk[9], rsr[9];
#pragma unroll
    for (int j = 0; j < 9; ++j) {
        int i = t + j * 1024;
        pk[j] = 0xFFFFFFFFu;
        if (i < used) {
            unsigned rec = recs[e0 + i];
            unsigned node = rec >> 17;
            rsr[j] = rec & 0x1FFFFu;
            unsigned r = atomicAdd(&cnt[node], 1u);
            pk[j] = node | (r << 8);
        }
    }
    __syncthreads();
    // phase 2: 256-entry exclusive scan (4 waves) + CSR/dinv emit
    if (t < NPB) {
        unsigned c = cnt[t];
        unsigned inc = c;
        int lane = t & 63, w = t >> 6;
#pragma unroll
        for (int d = 1; d < 64; d <<= 1) {
            unsigned o = __shfl_up(inc, d, 64);
            if (lane >= d) inc += o;
        }
        if (lane == 63) wtot[w] = inc;
        __syncthreads();
        unsigned wbase = 0;
        for (int i = 0; i < w; ++i) wbase += wtot[i];
        unsigned e = wbase + inc - c;
        ex[t] = e;
        float dv = rsqrtf((float)c + 1.0f);
        ldv[t] = dv;
        int node = b * NPB + t;
        if (node < n) {
            noff[node] = e0 + (int)e;
            nend[node] = e0 + (int)(e + c);
            dinv[node] = dv;
        }
    } else {
        __syncthreads();
    }
    __syncthreads();
    // phase 3: non-atomic LDS scatter from registers
#pragma unroll
    for (int j = 0; j < 9; ++j) {
        int i = t + j * 1024;
        if (i < used) {
            unsigned p = pk[j];
            lsort[ex[p & 255u] + (p >> 8)] = rsr[j];
        }
    }
    __syncthreads();
    // phase 4: coalesced write-out
    for (int i = t; i < used; i += 1024) srcs[e0 + i] = lsort[i];
    // phase 5 (fused): z = x * dinv for this block's 256 nodes (1 float4/thread)
    {
        int node = b * NPB + (t >> 2);
        if (node < n) {
            float4 v = ((const float4*)x)[(size_t)b * 1024 + t];
            float dv = ldv[t >> 2];
            v.x *= dv; v.y *= dv; v.z *= dv; v.w *= dv;
            ((float4*)z)[(size_t)b * 1024 + t] = v;
        }
    }
}

// atomic-free CSR aggregation — 64 nodes/block, 4 lanes/node, float4 gathers.
// s = sum over in-edges of hin[src,:] (+ hin[self,:]); t16 = (s)@W  (via LDS)
// mode 1: out = relu(dinv*t16 + bias) * dinv     (layer-1 -> y)
// mode 2: out = dinv*t16 + bias                  (final output)
__global__ void agg_csr_kernel(const float* __restrict__ hin, const unsigned* __restrict__ srcs,
                               const int* __restrict__ noff, const int* __restrict__ nend,
                               const float* __restrict__ dinv,
                               const float* __restrict__ W, const float* __restrict__ bias,
                               float* __restrict__ outp, int n, int mode) {
    __shared__ float a1[64][F + 1];
    __shared__ float Ws[F * F];
    int t = threadIdx.x;
    int g = t >> 2, c = t & 3;
    Ws[t] = W[t];
    int node = blockIdx.x * 64 + g;
    const float4* h4 = (const float4*)hin;
    float di = 0.f;
    if (node < n) {
        di = dinv[node];
        int e0 = noff[node], e1 = nend[node];
        float4 s0 = {0,0,0,0}, s1 = {0,0,0,0}, s2 = {0,0,0,0}, s3 = {0,0,0,0};
        int e = e0;
        for (; e + 4 <= e1; e += 4) {
            int ia = srcs[e], ib = srcs[e + 1], ic = srcs[e + 2], id = srcs[e + 3];
            float4 va = h4[(size_t)ia * 4 + c];
            float4 vb = h4[(size_t)ib * 4 + c];
            float4 vc = h4[(size_t)ic * 4 + c];
            float4 vd = h4[(size_t)id * 4 + c];
            s0.x += va.x; s0.y += va.y; s0.z += va.z; s0.w += va.w;
            s1.x += vb.x; s1.y += vb.y; s1.z += vb.z; s1.w += vb.w;
            s2.x += vc.x; s2.y += vc.y; s2.z += vc.z; s2.w += vc.w;
            s3.x += vd.x; s3.y += vd.y; s3.z += vd.z; s3.w += vd.w;
        }
        for (; e < e1; ++e) {
            float4 va = h4[(size_t)srcs[e] * 4 + c];
            s0.x += va.x; s0.y += va.y; s0.z += va.z; s0.w += va.w;
        }
        float4 self = h4[(size_t)node * 4 + c];
        a1[g][c * 4 + 0] = (s0.x + s1.x) + (s2.x + s3.x) + self.x;
        a1[g][c * 4 + 1] = (s0.y + s1.y) + (s2.y + s3.y) + self.y;
        a1[g][c * 4 + 2] = (s0.z + s1.z) + (s2.z + s3.z) + self.z;
        a1[g][c * 4 + 3] = (s0.w + s1.w) + (s2.w + s3.w) + self.w;
    }
    __syncthreads();
    if (node < n) {
        float4 o = {0.f, 0.f, 0.f, 0.f};
        int j = c * 4;
#pragma unroll
        for (int k = 0; k < F; ++k) {
            float ak = a1[g][k];
            o.x += ak * Ws[k * F + j + 0];
            o.y += ak * Ws[k * F + j + 1];
            o.z += ak * Ws[k * F + j + 2];
            o.w += ak * Ws[k * F + j + 3];
        }
        float4 bi = ((const float4*)bias)[c];
        o.x = di * o.x + bi.x; o.y = di * o.y + bi.y;
        o.z = di * o.z + bi.z; o.w = di * o.w + bi.w;
        if (mode == 1) {
            o.x = fmaxf(o.x, 0.f) * di; o.y = fmaxf(o.y, 0.f) * di;
            o.z = fmaxf(o.z, 0.f) * di; o.w = fmaxf(o.w, 0.f) * di;
        }
        ((float4*)outp)[(size_t)node * 4 + c] = o;
    }
}

// ========================= fallback (R1) kernels ============================

__global__ void deg_kernel(const int* __restrict__ dst, float* __restrict__ deg, int E) {
    int e = blockIdx.x * blockDim.x + threadIdx.x;
    if (e < E) atomicAdd(&deg[dst[e]], 1.0f);
}
__global__ void dinv_kernel(float* __restrict__ deg, int n) {
    int i = blockIdx.x * blockDim.x + threadIdx.x;
    if (i < n) deg[i] = rsqrtf(deg[i] + 1.0f);
}
__global__ void linear2_kernel(const float* __restrict__ in, const float* __restrict__ acc,
                               const float* __restrict__ dinv, const float* __restrict__ W,
                               const float* __restrict__ bias, float* __restrict__ out,
                               int n, int mode) {
    __shared__ float Ws[F * F];
    __shared__ float As[16][F + 1];
    int t = threadIdx.x;
    Ws[t] = W[t];
    int nb = t >> 4, j = t & 15;
    int i = blockIdx.x * 16 + nb;
    float di = 0.f, v = 0.f;
    if (i < n) {
        di = dinv[i]; v = in[i * F + j];
        if (mode) { v = di * (acc[i * F + j] + v) + bias[j]; v = fmaxf(v, 0.f); }
    }
    As[nb][j] = v;
    __syncthreads();
    if (i < n) {
        float s = 0.f;
#pragma unroll
        for (int k = 0; k < F; ++k) s += As[nb][k] * Ws[k * F + j];
        out[i * F + j] = s * di;
    }
}
__global__ void scatter_kernel(const int* __restrict__ src, const int* __restrict__ dst,
                               const float* __restrict__ h, float* __restrict__ acc, int E) {
    int t = blockIdx.x * blockDim.x + threadIdx.x;
    int e = t >> 4, j = t & 15;
    if (e < E) atomicAdd(&acc[dst[e] * F + j], h[src[e] * F + j]);
}
__global__ void out_kernel(const float* __restrict__ acc, const float* __restrict__ h,
                           const float* __restrict__ dinv, const float* __restrict__ bias,
                           float* __restrict__ out, int n) {
    int t = blockIdx.x * blockDim.x + threadIdx.x;
    if (t < n * F) {
        int i = t >> 4, j = t & 15;
        out[t] = dinv[i] * (acc[t] + h[t]) + bias[j];
    }
}

// ========================= launch ===========================================

extern "C" void kernel_launch(void* const* d_in, const int* in_sizes, int n_in,
                              void* d_out, int out_size, void* d_ws, size_t ws_size,
                              hipStream_t stream) {
    const float* x  = (const float*)d_in[0];
    const int*   ei = (const int*)d_in[1];
    const float* W1 = (const float*)d_in[2];
    const float* b1 = (const float*)d_in[3];
    const float* W2 = (const float*)d_in[4];
    const float* b2 = (const float*)d_in[5];
    float* outp = (float*)d_out;

    const int N = in_sizes[0] / F;
    const int E = in_sizes[1] / 2;
    const int* src = ei;
    const int* dst = ei + E;

    const int nb_rt = (N + NPB - 1) >> BSHIFT;
    const size_t RC = (size_t)NB * BCAP;           // 3,603,456 entries (> 16N)
    // ws layout (4B units): dinv[N] | z[16N] | recs[RC] (y aliases) | srcs[RC] |
    //                       noff[N] | nend[N] | cursor[16*NB]
    size_t need = sizeof(unsigned) * ((size_t)N * 19 + 2 * RC + 16 * NB);

    if (nb_rt == NB && E <= CH * 65535 && ws_size >= need) {
        float* dinv = (float*)d_ws;
        float* z = dinv + N;
        unsigned* recs = (unsigned*)(z + (size_t)F * N);
        float* y = (float*)recs;                   // alias: recs dead after sort2
        unsigned* srcs = recs + RC;
        int* noff = (int*)(srcs + RC);
        int* nend = noff + N;
        unsigned* cursor = (unsigned*)(nend + N);

        init_cursor_kernel<<<1, 512, 0, stream>>>(cursor);
        reorder_kernel<<<(E + CH - 1) / CH, 512, 0, stream>>>(src, dst, cursor, recs, E);
        sort2_kernel<<<NB, 1024, 0, stream>>>(recs, cursor, srcs, noff, nend, dinv, x, z, N);
        agg_csr_kernel<<<(N + 63) / 64, 256, 0, stream>>>(z, srcs, noff, nend, dinv, W1, b1, y, N, 1);
        agg_csr_kernel<<<(N + 63) / 64, 256, 0, stream>>>(y, srcs, noff, nend, dinv, W2, b2, outp, N, 2);
    } else {
        // R1 fallback: atomic scatter path (13.2MB ws)
        float* dinv = (float*)d_ws;
        float* h = dinv + N;
        float* acc = h + (size_t)F * N;
        hipMemsetAsync(dinv, 0, (size_t)N * sizeof(float), stream);
        hipMemsetAsync(acc, 0, (size_t)F * N * sizeof(float), stream);
        deg_kernel<<<(E + 255) / 256, 256, 0, stream>>>(dst, dinv, E);
        dinv_kernel<<<(N + 255) / 256, 256, 0, stream>>>(dinv, N);
        linear2_kernel<<<(N + 15) / 16, 256, 0, stream>>>(x, nullptr, dinv, W1, nullptr, h, N, 0);
        scatter_kernel<<<((size_t)E * F + 255) / 256, 256, 0, stream>>>(src, dst, h, acc, E);
        linear2_kernel<<<(N + 15) / 16, 256, 0, stream>>>(h, acc, dinv, W2, b1, h, N, 1);
        hipMemsetAsync(acc, 0, (size_t)F * N * sizeof(float), stream);
        scatter_kernel<<<((size_t)E * F + 255) / 256, 256, 0, stream>>>(src, dst, h, acc, E);
        out_kernel<<<((size_t)N * F + 255) / 256, 256, 0, stream>>>(acc, h, dinv, b2, outp, N);
    }
}